// Round 11
// baseline (228.937 us; speedup 1.0000x reference)
//
#include <hip/hip_runtime.h>

// B=4, C=64, H=48, HEADS=2, BSWIN=4, BIG={3,6,12,24}, SMALL={1,2,4,8}, NH=3, L=27, CPH=8
// P1 = 2x-pooled raw channels 16..63 (48 ch), bf16: [tz][b][ch][24][24][24]

typedef unsigned short u16;
static constexpr long S1 = 4L * 48 * 24 * 24 * 24;

typedef float f4 __attribute__((ext_vector_type(4)));
typedef u16 us8 __attribute__((ext_vector_type(8)));
typedef u16 us4 __attribute__((ext_vector_type(4)));

__device__ __forceinline__ f4 ntload(const float* p) {
    return __builtin_nontemporal_load((const f4*)p);
}
__device__ __forceinline__ void ntstore(float* p, f4 v) {
    __builtin_nontemporal_store(v, (f4*)p);
}
__device__ __forceinline__ f4 vmax4(f4 a, f4 b) {
    f4 r;
    r[0] = fmaxf(a[0], b[0]); r[1] = fmaxf(a[1], b[1]);
    r[2] = fmaxf(a[2], b[2]); r[3] = fmaxf(a[3], b[3]);
    return r;
}
__device__ __forceinline__ float b2f(u16 u) {
    union { unsigned int i; float f; } c; c.i = ((unsigned int)u) << 16; return c.f;
}
__device__ __forceinline__ u16 f2b(float x) {
    union { float f; unsigned int i; } c; c.f = x;
    unsigned int b = c.i;
    return (u16)((b + 0x7FFFu + ((b >> 16) & 1u)) >> 16);
}

// ---------------------------------------------------------------------------
// K1 body A: pool stage 1 (48->24), nt reads, bf16 out. pid=[b][c][zc] x tz
// ---------------------------------------------------------------------------
__device__ __forceinline__ void pool1_body(int pid,
                                           const float* __restrict__ q,
                                           const float* __restrict__ k,
                                           const float* __restrict__ v,
                                           u16* __restrict__ P1)
{
    const int tz = pid % 3;
    int rest = pid / 3;
    const int zc = rest % 12; rest /= 12;
    const int c = rest % 48;
    const int b = rest / 48;
    const float* in = tz == 0 ? q : (tz == 1 ? k : v);
    u16* o = P1 + (long)tz * S1;
    const float* base = in + ((long)b * 64 + 16 + c) * 110592;

    for (int i = threadIdx.x; i < 288; i += 256) {
        const int zl = i / 144;
        const int rem = i % 144;
        const int oy = rem / 6;
        const int qx = rem % 6;
        const int oz = zc * 2 + zl;
        const float* p = base + ((long)(2 * oz) * 48 + 2 * oy) * 48 + qx * 8;
        f4 r0a = ntload(p),        r0b = ntload(p + 4);
        f4 r1a = ntload(p + 48),   r1b = ntload(p + 52);
        f4 r2a = ntload(p + 2304), r2b = ntload(p + 2308);
        f4 r3a = ntload(p + 2352), r3b = ntload(p + 2356);
        f4 ma = vmax4(vmax4(r0a, r1a), vmax4(r2a, r3a));
        f4 mb = vmax4(vmax4(r0b, r1b), vmax4(r2b, r3b));
        us4 res;
        res[0] = f2b(fmaxf(ma[0], ma[1]));
        res[1] = f2b(fmaxf(ma[2], ma[3]));
        res[2] = f2b(fmaxf(mb[0], mb[1]));
        res[3] = f2b(fmaxf(mb[2], mb[3]));
        long oaddr = (((long)b * 48 + c) * 24 + oz) * 576 + oy * 24 + qx * 4;
        *(us4*)(o + oaddr) = res;
    }
}

// ---------------------------------------------------------------------------
// K1 body B: fused attn<0> + identity scatter<0>.
// ---------------------------------------------------------------------------
__device__ __forceinline__ void attn0_body(int aid, float* smem,
                                           const float* __restrict__ qsrc,
                                           const float* __restrict__ ksrc,
                                           const float* __restrict__ vsrc,
                                           const float* __restrict__ rpb,
                                           float* __restrict__ out)
{
    float* tile = smem;           // 8*3*8*28 = 5376
    float* bias = smem + 5376;    // 729
    const int tid = threadIdx.x;
    int rest = aid;
    const int half = rest & 1; rest >>= 1;
    const int Wy = rest % 16; rest /= 16;
    const int Wz = rest % 16; rest /= 16;
    const int head = rest % 2;
    const int b = rest / 2;

    for (int i = tid; i < 729; i += 256) {
        int m = i / 27, n = i % 27;
        int mi = m / 9, mj = (m / 3) % 3, mk = m % 3;
        int ni = n / 9, nj = (n / 3) % 3, nk = n % 3;
        int ridx = (mi - ni + 2) * 25 + (mj - nj + 2) * 5 + (mk - nk + 2);
        bias[i] = rpb[ridx * 2 + head];
    }

    for (int i = tid; i < 1296; i += 256) {
        int seg = i / 6;
        int off = (i % 6) * 4;
        int tz = seg / 72;
        int rem = seg % 72;
        int cph = rem / 9;
        int rem2 = rem % 9;
        int zt = rem2 / 3;
        int r = rem2 % 3;
        const float* src = tz == 0 ? qsrc : (tz == 1 ? ksrc : vsrc);
        long addr = ((((long)b * 64 + head * 8 + cph) * 48 + 3 * Wz + zt) * 48
                     + 3 * Wy + r) * 48 + half * 24 + off;
        f4 f = ntload(src + addr);
#pragma unroll
        for (int j = 0; j < 4; j++) {
            int xl = off + j;
            int wxl = xl / 3, tk = xl - wxl * 3;
            int tok = zt * 9 + r * 3 + tk;
            tile[((wxl * 3 + tz) * 8 + cph) * 28 + tok] = f[j];
        }
    }
    __syncthreads();

    const int wx = tid >> 5;
    const int lane = tid & 31;
    if (lane < 27) {
        const int m = lane;
        float* b0 = tile + wx * 672;
        const float* kb = b0 + 224;
        const float* vb = b0 + 448;
        float qr[8];
#pragma unroll
        for (int c = 0; c < 8; c++) qr[c] = b0[c * 28 + m];
        float s[27];
        float mx = -1e30f;
#pragma unroll
        for (int n = 0; n < 27; n++) {
            float acc = 0.f;
#pragma unroll
            for (int c = 0; c < 8; c++) acc += qr[c] * kb[c * 28 + n];
            acc *= 0.35355339059327373f;  // 1/sqrt(8)
            s[n] = acc;
            mx = fmaxf(mx, acc);
        }
        float sum = 0.f;
#pragma unroll
        for (int n = 0; n < 27; n++) {
            s[n] = __expf(s[n] - mx);
            sum += s[n];
        }
        float rs = 1.0f / sum;
        float o[8] = {0, 0, 0, 0, 0, 0, 0, 0};
#pragma unroll
        for (int n = 0; n < 27; n++) {
            float w = s[n] * rs + bias[m * 27 + n];
#pragma unroll
            for (int c = 0; c < 8; c++) o[c] += w * vb[c * 28 + n];
        }
#pragma unroll
        for (int c = 0; c < 8; c++) b0[c * 28 + m] = o[c];
    }
    __syncthreads();

    for (int i = tid; i < 432; i += 256) {
        int x4i = i % 6;
        int t2 = i / 6;
        int cph = t2 % 8; t2 /= 8;
        int y = t2 % 3;
        int zl = t2 / 3;
        f4 res;
#pragma unroll
        for (int e = 0; e < 4; e++) {
            int xl = x4i * 4 + e;
            int wxl = xl / 3, tk = xl - wxl * 3;
            int tok = zl * 9 + y * 3 + tk;
            res[e] = tile[wxl * 672 + cph * 28 + tok];
        }
        int z = 3 * Wz + zl;
        int Y = 3 * Wy + y;
        long oaddr = (((long)(b * 64 + head * 8 + cph) * 48 + z) * 48 + Y) * 48
                     + half * 24 + x4i * 4;
        ntstore(out + oaddr, res);
    }
}

__global__ void fused_k1(const float* __restrict__ q, const float* __restrict__ k,
                         const float* __restrict__ v, const float* __restrict__ rpb,
                         u16* __restrict__ P1, float* __restrict__ out)
{
    __shared__ __align__(16) float smem[6105];
    const int bx = blockIdx.x;
    if (bx < 8192 && (bx & 1) == 0) {
        attn0_body(bx >> 1, smem, q, k, v, rpb, out);
    } else {
        int pid = (bx < 8192) ? (bx >> 1) : (bx - 4096);
        pool1_body(pid, q, k, v, P1);
    }
}

// ---------------------------------------------------------------------------
// K2: attention + trilinear scatter for scales 1..3.
// Scatter restructured as jobs: one thread owns a contiguous x-run with fixed
// (cph, wp, wq); z/y taps pre-blended into v[kx] (12 LDS reads), each output
// is 2 FMAs; all stores aligned float4.
//   bx <  512 : class C (scale 3): 64 windows x 8 wp-slices
//   bx < 1024 : class B (scale 2): 128 rows x 4 wp-chunks
//   bx < 1536 : class A (scale 1): 512 rows
// ---------------------------------------------------------------------------
__device__ __forceinline__ void load_bias(float* bias, const float* __restrict__ rpb,
                                          int head, int tid)
{
    for (int i = tid; i < 729; i += 256) {
        int m = i / 27, n = i % 27;
        int mi = m / 9, mj = (m / 3) % 3, mk = m % 3;
        int ni = n / 9, nj = (n / 3) % 3, nk = n % 3;
        int ridx = (mi - ni + 2) * 25 + (mj - nj + 2) * 5 + (mk - nk + 2);
        bias[i] = rpb[ridx * 2 + head];
    }
}

__device__ __forceinline__ void attn_tile(float* tile, const float* bias, int tid, int NW)
{
    const int wx = tid >> 5;
    const int lane = tid & 31;
    if (wx < NW && lane < 27) {
        const int m = lane;
        float* b0 = tile + wx * 672;
        const float* kb = b0 + 224;
        const float* vb = b0 + 448;
        float qr[8];
#pragma unroll
        for (int c = 0; c < 8; c++) qr[c] = b0[c * 28 + m];
        float s[27];
        float mx = -1e30f;
#pragma unroll
        for (int n = 0; n < 27; n++) {
            float acc = 0.f;
#pragma unroll
            for (int c = 0; c < 8; c++) acc += qr[c] * kb[c * 28 + n];
            acc *= 0.35355339059327373f;
            s[n] = acc;
            mx = fmaxf(mx, acc);
        }
        float sum = 0.f;
#pragma unroll
        for (int n = 0; n < 27; n++) {
            s[n] = __expf(s[n] - mx);
            sum += s[n];
        }
        float rs = 1.0f / sum;
        float o[8] = {0, 0, 0, 0, 0, 0, 0, 0};
#pragma unroll
        for (int n = 0; n < 27; n++) {
            float w = s[n] * rs + bias[m * 27 + n];
#pragma unroll
            for (int c = 0; c < 8; c++) o[c] += w * vb[c * 28 + n];
        }
#pragma unroll
        for (int c = 0; c < 8; c++) b0[c * 28 + m] = o[c];
    }
}

// pre-blend the 4 z/y taps for the 3 x-tokens of one window (q-plane base bp)
__device__ __forceinline__ void preblend(const float* bp, int i0p, int i0q,
                                         float w00, float w01, float w10, float w11,
                                         float* v)
{
#pragma unroll
    for (int kx = 0; kx < 3; kx++) {
        const float* t = bp + i0p * 9 + i0q * 3 + kx;
        v[kx] = w00 * t[0] + w01 * t[3] + w10 * t[9] + w11 * t[12];
    }
}

__global__ void fused_k2(const u16* __restrict__ P1, const float* __restrict__ rpb,
                         float* __restrict__ out)
{
    __shared__ __align__(16) float smem[6105];
    float* tile = smem;
    float* bias = smem + 5376;
    const int tid = threadIdx.x;
    const int bx = blockIdx.x;

    if (bx >= 1024) {
        // ------------------ class A: scale 1 (bw=6, N1=8) ------------------
        int aid = bx - 1024;
        const int Wy = aid % 8; aid /= 8;
        const int Wz = aid % 8; aid /= 8;
        const int head = aid % 2;
        const int b = aid / 2;
        load_bias(bias, rpb, head, tid);
        for (int i = tid; i < 648; i += 256) {
            int xq = i % 3;
            int row = i / 3;
            int tz = row / 72;
            int rem = row % 72;
            int cph = rem / 9;
            int rem2 = rem % 9;
            int zt = rem2 / 3, r = rem2 % 3;
            const u16* p = P1 + (long)tz * S1 + ((long)b * 48 + head * 8 + cph) * 13824
                           + (3 * Wz + zt) * 576 + (3 * Wy + r) * 24 + xq * 8;
            us8 u = *(const us8*)p;
#pragma unroll
            for (int j = 0; j < 8; j++) {
                int xl = xq * 8 + j;
                int wxl = xl / 3, tk = xl - wxl * 3;
                tile[((wxl * 3 + tz) * 8 + cph) * 28 + zt * 9 + r * 3 + tk] = b2f(u[j]);
            }
        }
        __syncthreads();
        attn_tile(tile, bias, tid, 8);
        __syncthreads();

        // jobs: [cph(8)][wp(6)][wq(6)][winpair(4)] = 1152, each 12 x-floats
        const float inv = 2.0f / 5.0f;
        for (int i = tid; i < 1152; i += 256) {
            int wp2 = i % 4;
            int t = i / 4;
            int wq = t % 6; t /= 6;
            int wp = t % 6;
            int cph = t / 6;
            float posp = wp * inv; int i0p = min((int)posp, 1); float fp = posp - (float)i0p;
            float posq = wq * inv; int i0q = min((int)posq, 1); float fq = posq - (float)i0q;
            float w00 = (1.f - fp) * (1.f - fq), w01 = (1.f - fp) * fq;
            float w10 = fp * (1.f - fq),         w11 = fp * fq;
            float v0[3], v1[3];
            preblend(tile + (wp2 * 2) * 672 + cph * 28, i0p, i0q, w00, w01, w10, w11, v0);
            preblend(tile + (wp2 * 2 + 1) * 672 + cph * 28, i0p, i0q, w00, w01, w10, w11, v1);
            float ox[12];
#pragma unroll
            for (int x = 0; x < 12; x++) {
                int wr = (x >= 6) ? x - 6 : x;
                const float* vv = (x >= 6) ? v1 : v0;
                float posr = wr * inv; int i0r = min((int)posr, 1); float fr = posr - (float)i0r;
                ox[x] = (1.f - fr) * vv[i0r] + fr * vv[i0r + 1];
            }
            long rowb = (((long)(b * 64 + 16 + head * 8 + cph) * 48 + 6 * Wz + wp) * 48
                         + 6 * Wy + wq) * 48 + wp2 * 12;
#pragma unroll
            for (int s4 = 0; s4 < 3; s4++) {
                f4 res; res[0] = ox[4 * s4]; res[1] = ox[4 * s4 + 1];
                res[2] = ox[4 * s4 + 2]; res[3] = ox[4 * s4 + 3];
                ntstore(out + rowb + 4 * s4, res);
            }
        }
    } else if (bx >= 512) {
        // ---------- class B: scale 2 (bw=12, N1=4), 4 wp-chunks ------------
        int bid = bx - 512;
        const int chunk = bid % 4; bid /= 4;
        const int Wy = bid % 4; bid /= 4;
        const int Wz = bid % 4; bid /= 4;
        const int head = bid % 2;
        const int b = bid / 2;
        load_bias(bias, rpb, head, tid);
        for (int i = tid; i < 648; i += 256) {
            int xq = i % 3;
            int t = i / 3;
            int yt = t % 3; t /= 3;
            int zt = t % 3; t /= 3;
            int cph = t % 8;
            int tz = t / 8;
            const u16* base = P1 + (long)tz * S1 + ((long)b * 48 + 16 + head * 8 + cph) * 13824;
            float tv[4] = {-1e30f, -1e30f, -1e30f, -1e30f};
#pragma unroll
            for (int dz = 0; dz < 2; dz++)
#pragma unroll
                for (int dy = 0; dy < 2; dy++) {
                    const u16* p = base + (6 * Wz + 2 * zt + dz) * 576
                                   + (6 * Wy + 2 * yt + dy) * 24 + xq * 8;
                    us8 u = *(const us8*)p;
#pragma unroll
                    for (int j = 0; j < 4; j++)
                        tv[j] = fmaxf(tv[j], fmaxf(b2f(u[2 * j]), b2f(u[2 * j + 1])));
                }
#pragma unroll
            for (int j = 0; j < 4; j++) {
                int xt = xq * 4 + j;
                int wxl = xt / 3, tk = xt - wxl * 3;
                tile[((wxl * 3 + tz) * 8 + cph) * 28 + zt * 9 + yt * 3 + tk] = tv[j];
            }
        }
        __syncthreads();
        attn_tile(tile, bias, tid, 4);
        __syncthreads();

        // jobs: [cph(8)][wpl(3)][wq(12)][win(4)] = 1152, each 12 x-floats
        const float inv = 2.0f / 11.0f;
        for (int i = tid; i < 1152; i += 256) {
            int win = i % 4;
            int t = i / 4;
            int wq = t % 12; t /= 12;
            int wpl = t % 3;
            int cph = t / 3;
            int wp = chunk * 3 + wpl;
            float posp = wp * inv; int i0p = min((int)posp, 1); float fp = posp - (float)i0p;
            float posq = wq * inv; int i0q = min((int)posq, 1); float fq = posq - (float)i0q;
            float w00 = (1.f - fp) * (1.f - fq), w01 = (1.f - fp) * fq;
            float w10 = fp * (1.f - fq),         w11 = fp * fq;
            float v[3];
            preblend(tile + win * 672 + cph * 28, i0p, i0q, w00, w01, w10, w11, v);
            float ox[12];
#pragma unroll
            for (int wr = 0; wr < 12; wr++) {
                float posr = wr * inv; int i0r = min((int)posr, 1); float fr = posr - (float)i0r;
                ox[wr] = (1.f - fr) * v[i0r] + fr * v[i0r + 1];
            }
            long rowb = (((long)(b * 64 + 32 + head * 8 + cph) * 48 + 12 * Wz + wp) * 48
                         + 12 * Wy + wq) * 48 + win * 12;
#pragma unroll
            for (int s4 = 0; s4 < 3; s4++) {
                f4 res; res[0] = ox[4 * s4]; res[1] = ox[4 * s4 + 1];
                res[2] = ox[4 * s4 + 2]; res[3] = ox[4 * s4 + 3];
                ntstore(out + rowb + 4 * s4, res);
            }
        }
    } else {
        // ---------- class C: scale 3 (bw=24, N1=2), 8 wp-slices ------------
        int cid = bx;
        const int slice = cid % 8; cid /= 8;
        const int Wx = cid % 2; cid /= 2;
        const int Wy = cid % 2; cid /= 2;
        const int Wz = cid % 2; cid /= 2;
        const int head = cid % 2;
        const int b = cid / 2;
        load_bias(bias, rpb, head, tid);
        for (int i = tid; i < 216; i += 256) {
            int yt = i % 3;
            int t = i / 3;
            int zt = t % 3; t /= 3;
            int cph = t % 8;
            int tz = t / 8;
            const u16* base = P1 + (long)tz * S1 + ((long)b * 48 + 32 + head * 8 + cph) * 13824;
            float tv[3] = {-1e30f, -1e30f, -1e30f};
#pragma unroll
            for (int dz = 0; dz < 4; dz++)
#pragma unroll
                for (int dy = 0; dy < 4; dy++) {
                    const u16* p = base + (12 * Wz + 4 * zt + dz) * 576
                                   + (12 * Wy + 4 * yt + dy) * 24 + 12 * Wx;
#pragma unroll
                    for (int s3 = 0; s3 < 3; s3++) {
                        us4 u = *(const us4*)(p + 4 * s3);
                        tv[s3] = fmaxf(tv[s3],
                                       fmaxf(fmaxf(b2f(u[0]), b2f(u[1])),
                                             fmaxf(b2f(u[2]), b2f(u[3]))));
                    }
                }
#pragma unroll
            for (int s3 = 0; s3 < 3; s3++)
                tile[(tz * 8 + cph) * 28 + zt * 9 + yt * 3 + s3] = tv[s3];
        }
        __syncthreads();
        attn_tile(tile, bias, tid, 1);
        __syncthreads();

        // jobs: [cph(8)][wpl(3)][wq(24)] = 576, each 24 x-floats
        const float inv = 2.0f / 23.0f;
        for (int i = tid; i < 576; i += 256) {
            int wq = i % 24;
            int t = i / 24;
            int wpl = t % 3;
            int cph = t / 3;
            int wp = slice * 3 + wpl;
            float posp = wp * inv; int i0p = min((int)posp, 1); float fp = posp - (float)i0p;
            float posq = wq * inv; int i0q = min((int)posq, 1); float fq = posq - (float)i0q;
            float w00 = (1.f - fp) * (1.f - fq), w01 = (1.f - fp) * fq;
            float w10 = fp * (1.f - fq),         w11 = fp * fq;
            float v[3];
            preblend(tile + cph * 28, i0p, i0q, w00, w01, w10, w11, v);
            long rowb = (((long)(b * 64 + 48 + head * 8 + cph) * 48 + 24 * Wz + wp) * 48
                         + 24 * Wy + wq) * 48 + 24 * Wx;
#pragma unroll
            for (int s4 = 0; s4 < 6; s4++) {
                f4 res;
#pragma unroll
                for (int e = 0; e < 4; e++) {
                    int wr = s4 * 4 + e;
                    float posr = wr * inv; int i0r = min((int)posr, 1);
                    float fr = posr - (float)i0r;
                    res[e] = (1.f - fr) * v[i0r] + fr * v[i0r + 1];
                }
                ntstore(out + rowb + 4 * s4, res);
            }
        }
    }
}

extern "C" void kernel_launch(void* const* d_in, const int* in_sizes, int n_in,
                              void* d_out, int out_size, void* d_ws, size_t ws_size,
                              hipStream_t stream)
{
    const float* q   = (const float*)d_in[0];
    const float* k   = (const float*)d_in[1];
    const float* v   = (const float*)d_in[2];
    const float* rpb = (const float*)d_in[3];
    float* out = (float*)d_out;
    u16* P1 = (u16*)d_ws;

    // K1: pool stage 1 (bf16 out) co-launched with fused attn0+scatter0
    fused_k1<<<11008, 256, 0, stream>>>(q, k, v, rpb, P1, out);

    // K2: attention + register-preblended trilinear scatter, scales 1..3
    fused_k2<<<1536, 256, 0, stream>>>(P1, rpb, out);
}

// Round 12
// 161.124 us; speedup vs baseline: 1.4209x; 1.4209x over previous
//
#include <hip/hip_runtime.h>

// B=4, C=64, H=48, HEADS=2, BSWIN=4, BIG={3,6,12,24}, SMALL={1,2,4,8}, NH=3, L=27, CPH=8
// P1 = 2x-pooled raw channels 16..63 (48 ch), bf16: [tz][b][ch][24][24][24]

typedef unsigned short u16;
static constexpr long S1 = 4L * 48 * 24 * 24 * 24;

typedef float f4 __attribute__((ext_vector_type(4)));
typedef u16 us8 __attribute__((ext_vector_type(8)));
typedef u16 us4 __attribute__((ext_vector_type(4)));

__device__ __forceinline__ f4 ntload(const float* p) {
    return __builtin_nontemporal_load((const f4*)p);
}
__device__ __forceinline__ void ntstore(float* p, f4 v) {
    __builtin_nontemporal_store(v, (f4*)p);
}
__device__ __forceinline__ f4 vmax4(f4 a, f4 b) {
    f4 r;
    r[0] = fmaxf(a[0], b[0]); r[1] = fmaxf(a[1], b[1]);
    r[2] = fmaxf(a[2], b[2]); r[3] = fmaxf(a[3], b[3]);
    return r;
}
__device__ __forceinline__ float b2f(u16 u) {
    union { unsigned int i; float f; } c; c.i = ((unsigned int)u) << 16; return c.f;
}
__device__ __forceinline__ u16 f2b(float x) {
    union { float f; unsigned int i; } c; c.f = x;
    unsigned int b = c.i;
    return (u16)((b + 0x7FFFu + ((b >> 16) & 1u)) >> 16);
}

// ---------------------------------------------------------------------------
// K1 (unchanged from round 10): pool1 (bf16 out) + fused attn0/scatter0
// ---------------------------------------------------------------------------
__device__ __forceinline__ void pool1_body(int pid,
                                           const float* __restrict__ q,
                                           const float* __restrict__ k,
                                           const float* __restrict__ v,
                                           u16* __restrict__ P1)
{
    const int tz = pid % 3;
    int rest = pid / 3;
    const int zc = rest % 12; rest /= 12;
    const int c = rest % 48;
    const int b = rest / 48;
    const float* in = tz == 0 ? q : (tz == 1 ? k : v);
    u16* o = P1 + (long)tz * S1;
    const float* base = in + ((long)b * 64 + 16 + c) * 110592;

    for (int i = threadIdx.x; i < 288; i += 256) {
        const int zl = i / 144;
        const int rem = i % 144;
        const int oy = rem / 6;
        const int qx = rem % 6;
        const int oz = zc * 2 + zl;
        const float* p = base + ((long)(2 * oz) * 48 + 2 * oy) * 48 + qx * 8;
        f4 r0a = ntload(p),        r0b = ntload(p + 4);
        f4 r1a = ntload(p + 48),   r1b = ntload(p + 52);
        f4 r2a = ntload(p + 2304), r2b = ntload(p + 2308);
        f4 r3a = ntload(p + 2352), r3b = ntload(p + 2356);
        f4 ma = vmax4(vmax4(r0a, r1a), vmax4(r2a, r3a));
        f4 mb = vmax4(vmax4(r0b, r1b), vmax4(r2b, r3b));
        us4 res;
        res[0] = f2b(fmaxf(ma[0], ma[1]));
        res[1] = f2b(fmaxf(ma[2], ma[3]));
        res[2] = f2b(fmaxf(mb[0], mb[1]));
        res[3] = f2b(fmaxf(mb[2], mb[3]));
        long oaddr = (((long)b * 48 + c) * 24 + oz) * 576 + oy * 24 + qx * 4;
        *(us4*)(o + oaddr) = res;
    }
}

__device__ __forceinline__ void attn0_body(int aid, float* smem,
                                           const float* __restrict__ qsrc,
                                           const float* __restrict__ ksrc,
                                           const float* __restrict__ vsrc,
                                           const float* __restrict__ rpb,
                                           float* __restrict__ out)
{
    float* tile = smem;           // 8*3*8*28 = 5376
    float* bias = smem + 5376;    // 729
    const int tid = threadIdx.x;
    int rest = aid;
    const int half = rest & 1; rest >>= 1;
    const int Wy = rest % 16; rest /= 16;
    const int Wz = rest % 16; rest /= 16;
    const int head = rest % 2;
    const int b = rest / 2;

    for (int i = tid; i < 729; i += 256) {
        int m = i / 27, n = i % 27;
        int mi = m / 9, mj = (m / 3) % 3, mk = m % 3;
        int ni = n / 9, nj = (n / 3) % 3, nk = n % 3;
        int ridx = (mi - ni + 2) * 25 + (mj - nj + 2) * 5 + (mk - nk + 2);
        bias[i] = rpb[ridx * 2 + head];
    }

    for (int i = tid; i < 1296; i += 256) {
        int seg = i / 6;
        int off = (i % 6) * 4;
        int tz = seg / 72;
        int rem = seg % 72;
        int cph = rem / 9;
        int rem2 = rem % 9;
        int zt = rem2 / 3;
        int r = rem2 % 3;
        const float* src = tz == 0 ? qsrc : (tz == 1 ? ksrc : vsrc);
        long addr = ((((long)b * 64 + head * 8 + cph) * 48 + 3 * Wz + zt) * 48
                     + 3 * Wy + r) * 48 + half * 24 + off;
        f4 f = ntload(src + addr);
#pragma unroll
        for (int j = 0; j < 4; j++) {
            int xl = off + j;
            int wxl = xl / 3, tk = xl - wxl * 3;
            int tok = zt * 9 + r * 3 + tk;
            tile[((wxl * 3 + tz) * 8 + cph) * 28 + tok] = f[j];
        }
    }
    __syncthreads();

    const int wx = tid >> 5;
    const int lane = tid & 31;
    if (lane < 27) {
        const int m = lane;
        float* b0 = tile + wx * 672;
        const float* kb = b0 + 224;
        const float* vb = b0 + 448;
        float qr[8];
#pragma unroll
        for (int c = 0; c < 8; c++) qr[c] = b0[c * 28 + m];
        float s[27];
        float mx = -1e30f;
#pragma unroll
        for (int n = 0; n < 27; n++) {
            float acc = 0.f;
#pragma unroll
            for (int c = 0; c < 8; c++) acc += qr[c] * kb[c * 28 + n];
            acc *= 0.35355339059327373f;  // 1/sqrt(8)
            s[n] = acc;
            mx = fmaxf(mx, acc);
        }
        float sum = 0.f;
#pragma unroll
        for (int n = 0; n < 27; n++) {
            s[n] = __expf(s[n] - mx);
            sum += s[n];
        }
        float rs = 1.0f / sum;
        float o[8] = {0, 0, 0, 0, 0, 0, 0, 0};
#pragma unroll
        for (int n = 0; n < 27; n++) {
            float w = s[n] * rs + bias[m * 27 + n];
#pragma unroll
            for (int c = 0; c < 8; c++) o[c] += w * vb[c * 28 + n];
        }
#pragma unroll
        for (int c = 0; c < 8; c++) b0[c * 28 + m] = o[c];
    }
    __syncthreads();

    for (int i = tid; i < 432; i += 256) {
        int x4i = i % 6;
        int t2 = i / 6;
        int cph = t2 % 8; t2 /= 8;
        int y = t2 % 3;
        int zl = t2 / 3;
        f4 res;
#pragma unroll
        for (int e = 0; e < 4; e++) {
            int xl = x4i * 4 + e;
            int wxl = xl / 3, tk = xl - wxl * 3;
            int tok = zl * 9 + y * 3 + tk;
            res[e] = tile[wxl * 672 + cph * 28 + tok];
        }
        int z = 3 * Wz + zl;
        int Y = 3 * Wy + y;
        long oaddr = (((long)(b * 64 + head * 8 + cph) * 48 + z) * 48 + Y) * 48
                     + half * 24 + x4i * 4;
        ntstore(out + oaddr, res);
    }
}

__global__ void fused_k1(const float* __restrict__ q, const float* __restrict__ k,
                         const float* __restrict__ v, const float* __restrict__ rpb,
                         u16* __restrict__ P1, float* __restrict__ out)
{
    __shared__ __align__(16) float smem[6105];
    const int bx = blockIdx.x;
    if (bx < 8192 && (bx & 1) == 0) {
        attn0_body(bx >> 1, smem, q, k, v, rpb, out);
    } else {
        int pid = (bx < 8192) ? (bx >> 1) : (bx - 4096);
        pool1_body(pid, q, k, v, P1);
    }
}

// ---------------------------------------------------------------------------
// K2: attention + trilinear scatter for scales 1..3.
// Round-10 job decomposition (coalesced f4 stores) + per-thread register
// preblend (12-24 LDS reads per f4 instead of 32) + window stride 676
// (bank-spread; 672 % 32 == 0 was all-bank-0 across windows).
// ---------------------------------------------------------------------------
static constexpr int WS = 676;   // padded per-window tile stride (floats)

__device__ __forceinline__ void load_bias(float* bias, const float* __restrict__ rpb,
                                          int head, int tid)
{
    for (int i = tid; i < 729; i += 256) {
        int m = i / 27, n = i % 27;
        int mi = m / 9, mj = (m / 3) % 3, mk = m % 3;
        int ni = n / 9, nj = (n / 3) % 3, nk = n % 3;
        int ridx = (mi - ni + 2) * 25 + (mj - nj + 2) * 5 + (mk - nk + 2);
        bias[i] = rpb[ridx * 2 + head];
    }
}

__device__ __forceinline__ void attn_tile(float* tile, const float* bias, int tid, int NW)
{
    const int wx = tid >> 5;
    const int lane = tid & 31;
    if (wx < NW && lane < 27) {
        const int m = lane;
        float* b0 = tile + wx * WS;
        const float* kb = b0 + 224;
        const float* vb = b0 + 448;
        float qr[8];
#pragma unroll
        for (int c = 0; c < 8; c++) qr[c] = b0[c * 28 + m];
        float s[27];
        float mx = -1e30f;
#pragma unroll
        for (int n = 0; n < 27; n++) {
            float acc = 0.f;
#pragma unroll
            for (int c = 0; c < 8; c++) acc += qr[c] * kb[c * 28 + n];
            acc *= 0.35355339059327373f;
            s[n] = acc;
            mx = fmaxf(mx, acc);
        }
        float sum = 0.f;
#pragma unroll
        for (int n = 0; n < 27; n++) {
            s[n] = __expf(s[n] - mx);
            sum += s[n];
        }
        float rs = 1.0f / sum;
        float o[8] = {0, 0, 0, 0, 0, 0, 0, 0};
#pragma unroll
        for (int n = 0; n < 27; n++) {
            float w = s[n] * rs + bias[m * 27 + n];
#pragma unroll
            for (int c = 0; c < 8; c++) o[c] += w * vb[c * 28 + n];
        }
#pragma unroll
        for (int c = 0; c < 8; c++) b0[c * 28 + m] = o[c];
    }
}

// blend the 4 z/y taps for the 3 x-tokens of one window's q-plane (bp)
__device__ __forceinline__ void preblend(const float* bp, int i0p, int i0q,
                                         float w00, float w01, float w10, float w11,
                                         float* v)
{
#pragma unroll
    for (int kx = 0; kx < 3; kx++) {
        const float* t = bp + i0p * 9 + i0q * 3 + kx;
        v[kx] = w00 * t[0] + w01 * t[3] + w10 * t[9] + w11 * t[12];
    }
}

__global__ void fused_k2(const u16* __restrict__ P1, const float* __restrict__ rpb,
                         float* __restrict__ out)
{
    __shared__ __align__(16) float smem[8 * WS + 729];
    float* tile = smem;
    float* bias = smem + 8 * WS;
    const int tid = threadIdx.x;
    const int bx = blockIdx.x;

    if (bx >= 1024) {
        // ------------------ class A: scale 1 (bw=6, N1=8) ------------------
        int aid = bx - 1024;
        const int Wy = aid % 8; aid /= 8;
        const int Wz = aid % 8; aid /= 8;
        const int head = aid % 2;
        const int b = aid / 2;
        load_bias(bias, rpb, head, tid);
        for (int i = tid; i < 648; i += 256) {
            int xq = i % 3;
            int row = i / 3;
            int tz = row / 72;
            int rem = row % 72;
            int cph = rem / 9;
            int rem2 = rem % 9;
            int zt = rem2 / 3, r = rem2 % 3;
            const u16* p = P1 + (long)tz * S1 + ((long)b * 48 + head * 8 + cph) * 13824
                           + (3 * Wz + zt) * 576 + (3 * Wy + r) * 24 + xq * 8;
            us8 u = *(const us8*)p;
#pragma unroll
            for (int j = 0; j < 8; j++) {
                int xl = xq * 8 + j;
                int wxl = xl / 3, tk = xl - wxl * 3;
                tile[wxl * WS + (tz * 8 + cph) * 28 + zt * 9 + r * 3 + tk] = b2f(u[j]);
            }
        }
        __syncthreads();
        attn_tile(tile, bias, tid, 8);
        __syncthreads();

        const float inv = 2.0f / 5.0f;
        for (int i = tid; i < 3456; i += 256) {
            int x4 = i % 12;
            int t2 = i / 12;
            int cph = t2 % 8; t2 /= 8;
            int wq = t2 % 6;
            int wp = t2 / 6;
            float posp = wp * inv; int i0p = min((int)posp, 1); float fp = posp - (float)i0p;
            float posq = wq * inv; int i0q = min((int)posq, 1); float fq = posq - (float)i0q;
            float w00 = (1.f - fp) * (1.f - fq), w01 = (1.f - fp) * fq;
            float w10 = fp * (1.f - fq),         w11 = fp * fq;
            int Wa = (4 * x4) / 6, Wb = (4 * x4 + 3) / 6;
            float va[3], vb2[3];
            preblend(tile + Wa * WS + cph * 28, i0p, i0q, w00, w01, w10, w11, va);
            preblend(tile + Wb * WS + cph * 28, i0p, i0q, w00, w01, w10, w11, vb2);
            f4 res;
#pragma unroll
            for (int e = 0; e < 4; e++) {
                int xg = 4 * x4 + e;
                int Wx = xg / 6, wr = xg - 6 * Wx;
                const float* vv = (Wx == Wa) ? va : vb2;
                float posr = wr * inv; int i0r = min((int)posr, 1); float fr = posr - (float)i0r;
                res[e] = (1.f - fr) * vv[i0r] + fr * vv[i0r + 1];
            }
            long oaddr = (((long)(b * 64 + 16 + head * 8 + cph) * 48 + 6 * Wz + wp) * 48
                          + 6 * Wy + wq) * 48 + x4 * 4;
            ntstore(out + oaddr, res);
        }
    } else if (bx >= 512) {
        // ---------- class B: scale 2 (bw=12, N1=4), 4 wp-chunks ------------
        int bid = bx - 512;
        const int chunk = bid % 4; bid /= 4;
        const int Wy = bid % 4; bid /= 4;
        const int Wz = bid % 4; bid /= 4;
        const int head = bid % 2;
        const int b = bid / 2;
        load_bias(bias, rpb, head, tid);
        for (int i = tid; i < 648; i += 256) {
            int xq = i % 3;
            int t = i / 3;
            int yt = t % 3; t /= 3;
            int zt = t % 3; t /= 3;
            int cph = t % 8;
            int tz = t / 8;
            const u16* base = P1 + (long)tz * S1 + ((long)b * 48 + 16 + head * 8 + cph) * 13824;
            float tv[4] = {-1e30f, -1e30f, -1e30f, -1e30f};
#pragma unroll
            for (int dz = 0; dz < 2; dz++)
#pragma unroll
                for (int dy = 0; dy < 2; dy++) {
                    const u16* p = base + (6 * Wz + 2 * zt + dz) * 576
                                   + (6 * Wy + 2 * yt + dy) * 24 + xq * 8;
                    us8 u = *(const us8*)p;
#pragma unroll
                    for (int j = 0; j < 4; j++)
                        tv[j] = fmaxf(tv[j], fmaxf(b2f(u[2 * j]), b2f(u[2 * j + 1])));
                }
#pragma unroll
            for (int j = 0; j < 4; j++) {
                int xt = xq * 4 + j;
                int wxl = xt / 3, tk = xt - wxl * 3;
                tile[wxl * WS + (tz * 8 + cph) * 28 + zt * 9 + yt * 3 + tk] = tv[j];
            }
        }
        __syncthreads();
        attn_tile(tile, bias, tid, 4);
        __syncthreads();

        const float inv = 2.0f / 11.0f;
        for (int i = tid; i < 3456; i += 256) {
            int x4 = i % 12;
            int t2 = i / 12;
            int cph = t2 % 8; t2 /= 8;
            int wq = t2 % 12;
            int wp = chunk * 3 + t2 / 12;
            float posp = wp * inv; int i0p = min((int)posp, 1); float fp = posp - (float)i0p;
            float posq = wq * inv; int i0q = min((int)posq, 1); float fq = posq - (float)i0q;
            float w00 = (1.f - fp) * (1.f - fq), w01 = (1.f - fp) * fq;
            float w10 = fp * (1.f - fq),         w11 = fp * fq;
            int W = x4 / 3;   // 4-float run never crosses a 12-wide window
            float v[3];
            preblend(tile + W * WS + cph * 28, i0p, i0q, w00, w01, w10, w11, v);
            f4 res;
#pragma unroll
            for (int e = 0; e < 4; e++) {
                int xg = 4 * x4 + e;
                int wr = xg - 12 * W;
                float posr = wr * inv; int i0r = min((int)posr, 1); float fr = posr - (float)i0r;
                res[e] = (1.f - fr) * v[i0r] + fr * v[i0r + 1];
            }
            long oaddr = (((long)(b * 64 + 32 + head * 8 + cph) * 48 + 12 * Wz + wp) * 48
                          + 12 * Wy + wq) * 48 + x4 * 4;
            ntstore(out + oaddr, res);
        }
    } else {
        // ---------- class C: scale 3 (bw=24, N1=2), 8 wp-slices ------------
        int cid = bx;
        const int slice = cid % 8; cid /= 8;
        const int Wx = cid % 2; cid /= 2;
        const int Wy = cid % 2; cid /= 2;
        const int Wz = cid % 2; cid /= 2;
        const int head = cid % 2;
        const int b = cid / 2;
        load_bias(bias, rpb, head, tid);
        for (int i = tid; i < 216; i += 256) {
            int yt = i % 3;
            int t = i / 3;
            int zt = t % 3; t /= 3;
            int cph = t % 8;
            int tz = t / 8;
            const u16* base = P1 + (long)tz * S1 + ((long)b * 48 + 32 + head * 8 + cph) * 13824;
            float tv[3] = {-1e30f, -1e30f, -1e30f};
#pragma unroll
            for (int dz = 0; dz < 4; dz++)
#pragma unroll
                for (int dy = 0; dy < 4; dy++) {
                    const u16* p = base + (12 * Wz + 4 * zt + dz) * 576
                                   + (12 * Wy + 4 * yt + dy) * 24 + 12 * Wx;
#pragma unroll
                    for (int s3 = 0; s3 < 3; s3++) {
                        us4 u = *(const us4*)(p + 4 * s3);
                        tv[s3] = fmaxf(tv[s3],
                                       fmaxf(fmaxf(b2f(u[0]), b2f(u[1])),
                                             fmaxf(b2f(u[2]), b2f(u[3]))));
                    }
                }
#pragma unroll
            for (int s3 = 0; s3 < 3; s3++)
                tile[(tz * 8 + cph) * 28 + zt * 9 + yt * 3 + s3] = tv[s3];
        }
        __syncthreads();
        attn_tile(tile, bias, tid, 1);
        __syncthreads();

        const float inv = 2.0f / 23.0f;
        for (int i = tid; i < 3456; i += 256) {
            int x4 = i % 6;
            int t2 = i / 6;
            int cph = t2 % 8; t2 /= 8;
            int wq = t2 % 24;
            int wp = slice * 3 + t2 / 24;
            float posp = wp * inv; int i0p = min((int)posp, 1); float fp = posp - (float)i0p;
            float posq = wq * inv; int i0q = min((int)posq, 1); float fq = posq - (float)i0q;
            float w00 = (1.f - fp) * (1.f - fq), w01 = (1.f - fp) * fq;
            float w10 = fp * (1.f - fq),         w11 = fp * fq;
            float v[3];
            preblend(tile + cph * 28, i0p, i0q, w00, w01, w10, w11, v);
            f4 res;
#pragma unroll
            for (int e = 0; e < 4; e++) {
                int wr = 4 * x4 + e;
                float posr = wr * inv; int i0r = min((int)posr, 1); float fr = posr - (float)i0r;
                res[e] = (1.f - fr) * v[i0r] + fr * v[i0r + 1];
            }
            long oaddr = (((long)(b * 64 + 48 + head * 8 + cph) * 48 + 24 * Wz + wp) * 48
                          + 24 * Wy + wq) * 48 + 24 * Wx + x4 * 4;
            ntstore(out + oaddr, res);
        }
    }
}

extern "C" void kernel_launch(void* const* d_in, const int* in_sizes, int n_in,
                              void* d_out, int out_size, void* d_ws, size_t ws_size,
                              hipStream_t stream)
{
    const float* q   = (const float*)d_in[0];
    const float* k   = (const float*)d_in[1];
    const float* v   = (const float*)d_in[2];
    const float* rpb = (const float*)d_in[3];
    float* out = (float*)d_out;
    u16* P1 = (u16*)d_ws;

    // K1: pool stage 1 (bf16 out) co-launched with fused attn0+scatter0
    fused_k1<<<11008, 256, 0, stream>>>(q, k, v, rpb, P1, out);

    // K2: attention + per-thread-preblended trilinear scatter (coalesced stores)
    fused_k2<<<1536, 256, 0, stream>>>(P1, rpb, out);
}